// Round 9
// baseline (188.509 us; speedup 1.0000x reference)
//
#include <hip/hip_runtime.h>
#include <stdint.h>

// Problem constants (from reference)
#define NNODES 50000
#define NEDGES 1000000
#define DIM    64
#define NREL   8
#define NBUCK  391          // ceil(50000/128); bucket = dst >> 7 (128-node range)
#define BCAP   2944         // per-bucket staging capacity (expected ~2558, +7.6 sigma)
#define KEYS   1024         // 128 nodes x 8 rels per bucket
#define NBLK   3125         // 50000 / 16 output blocks
#define APITCH 584          // LDS bf16 tile pitch (576 + 8)

typedef __attribute__((ext_vector_type(8))) short short8;
typedef __attribute__((ext_vector_type(4))) float float4v;
typedef __attribute__((ext_vector_type(4))) unsigned short us4;

__device__ __forceinline__ float bf2f(unsigned short u) {
  return __uint_as_float(((unsigned int)u) << 16);
}
__device__ __forceinline__ unsigned short f2bf(float f) {
  unsigned int u = __float_as_uint(f);
  unsigned int r = (u + 0x7FFF + ((u >> 16) & 1)) >> 16;   // round-nearest-even
  return (unsigned short)r;
}

#define CASTBLK ((NNODES * DIM / 4 + 255) / 256)
#define PREPBLK ((18 * 4 * 64 * 8 + 255) / 256)

// K0: fused prep (B fragments + bias) and x f32->bf16 cast; zero bucket_cursor.
__global__ void prep_cast_kernel(const float* __restrict__ Wlin,
                                 const float* __restrict__ Wself,
                                 const float* __restrict__ blin,
                                 const float* __restrict__ bself,
                                 const float4* __restrict__ x4,
                                 unsigned short* __restrict__ Bf2,
                                 float* __restrict__ bsum,
                                 us4* __restrict__ xb,
                                 int* __restrict__ bucket_cursor) {
  int gt = blockIdx.x * 256 + threadIdx.x;
  if (gt < NBUCK) bucket_cursor[gt] = 0;
  if (gt < 64) bsum[gt] = blin[gt] + bself[gt];
  if (blockIdx.x < CASTBLK) {
    int t = gt;
    if (t < NNODES * DIM / 4) {
      float4 v = x4[t];
      us4 o;
      o.x = f2bf(v.x); o.y = f2bf(v.y); o.z = f2bf(v.z); o.w = f2bf(v.w);
      xb[t] = o;
    }
  } else {
    int t = (blockIdx.x - CASTBLK) * 256 + threadIdx.x;
    if (t < 18 * 4 * 64 * 8) {
      int j  = t & 7;
      int l  = (t >> 3) & 63;
      int ct = (t >> 9) & 3;
      int ks = t >> 11;
      int k = ks * 32 + (l >> 4) * 8 + j;
      int c = ct * 16 + (l & 15);
      float v = (k < 512) ? Wlin[(size_t)k * 64 + c] : Wself[(size_t)(k - 512) * 64 + c];
      Bf2[t] = f2bf(v);
    }
  }
}

// K1: binned scatter with block-local LDS counting sort + coalesced run flush.
// Record: x = src(16) | rel(3)<<16 | dst_low7(7)<<19, y = w bits.
__global__ __launch_bounds__(1024) void binscatter_kernel(
    const int4* __restrict__ src4, const int4* __restrict__ dst4,
    const int4* __restrict__ rel4, const float4* __restrict__ w4,
    int* __restrict__ bucket_cursor, uint2* __restrict__ staged, int E4) {
  __shared__ int lhist[NBUCK];
  __shared__ int lscan[NBUCK];
  __shared__ int lbaseg[NBUCK];
  __shared__ uint2 lrec[4096];              // 32 KB
  __shared__ unsigned short lbuck[4096];    // 8 KB
  int tid = threadIdx.x;
  if (tid < NBUCK) lhist[tid] = 0;
  __syncthreads();
  int t = blockIdx.x * 1024 + tid;
  bool valid = t < E4;
  int4 s = {0,0,0,0}, d = {0,0,0,0}, r = {0,0,0,0};
  float4 w = {0.f,0.f,0.f,0.f};
  if (valid) { s = src4[t]; d = dst4[t]; r = rel4[t]; w = w4[t]; }
  int b0=0,b1=0,b2=0,b3=0,p0=0,p1=0,p2=0,p3=0;
  if (valid) {
    b0 = d.x >> 7; p0 = atomicAdd(&lhist[b0], 1);
    b1 = d.y >> 7; p1 = atomicAdd(&lhist[b1], 1);
    b2 = d.z >> 7; p2 = atomicAdd(&lhist[b2], 1);
    b3 = d.w >> 7; p3 = atomicAdd(&lhist[b3], 1);
  }
  __syncthreads();
  if (tid < 64) {                 // wave 0: exclusive scan of 391 counts
    int carry = 0;
    #pragma unroll
    for (int c = 0; c < 7; c++) {
      int i = c * 64 + tid;
      int v = (i < NBUCK) ? lhist[i] : 0;
      int inc = v;
      #pragma unroll
      for (int dd = 1; dd < 64; dd <<= 1) {
        int tt = __shfl_up(inc, dd);
        if (tid >= dd) inc += tt;
      }
      if (i < NBUCK) lscan[i] = carry + inc - v;
      carry += __shfl(inc, 63);
    }
  }
  __syncthreads();
  if (valid) {
    int q;
    q = lscan[b0] + p0; lrec[q] = make_uint2((unsigned)s.x | ((unsigned)r.x << 16) | ((unsigned)(d.x & 127) << 19), __float_as_uint(w.x)); lbuck[q] = (unsigned short)b0;
    q = lscan[b1] + p1; lrec[q] = make_uint2((unsigned)s.y | ((unsigned)r.y << 16) | ((unsigned)(d.y & 127) << 19), __float_as_uint(w.y)); lbuck[q] = (unsigned short)b1;
    q = lscan[b2] + p2; lrec[q] = make_uint2((unsigned)s.z | ((unsigned)r.z << 16) | ((unsigned)(d.z & 127) << 19), __float_as_uint(w.z)); lbuck[q] = (unsigned short)b2;
    q = lscan[b3] + p3; lrec[q] = make_uint2((unsigned)s.w | ((unsigned)r.w << 16) | ((unsigned)(d.w & 127) << 19), __float_as_uint(w.w)); lbuck[q] = (unsigned short)b3;
  }
  if (tid < NBUCK && lhist[tid] > 0)
    lbaseg[tid] = atomicAdd(&bucket_cursor[tid], lhist[tid]);
  __syncthreads();
  int cntblk = NEDGES - blockIdx.x * 4096;
  if (cntblk > 4096) cntblk = 4096;
  for (int i = tid; i < cntblk; i += 1024) {     // linear LDS read, run-coalesced store
    int b = lbuck[i];
    int idx = lbaseg[b] + (i - lscan[b]);
    if (idx < BCAP) staged[(size_t)b * BCAP + idx] = lrec[i];
  }
}

// K2: per-bucket: LDS-cache records, 1024-key hist+scan, write per-(node,rel)
// segment offsets roff[] and meta = (src*128 | rel, w/deg) grouped by (node,rel).
__global__ __launch_bounds__(1024) void csrbuild_kernel(
    const int* __restrict__ bucket_cursor,
    const uint2* __restrict__ staged, uint2* __restrict__ meta, int* __restrict__ roff) {
  __shared__ uint2 cache[BCAP];                 // 23.0 KB
  __shared__ int   nhist[KEYS];
  __shared__ int   ncur[KEYS];
  __shared__ float degf[KEYS];
  __shared__ int   base_s;
  int b = blockIdx.x;
  int tid = threadIdx.x;
  int cnt  = bucket_cursor[b];
  if (cnt > BCAP) cnt = BCAP;
  if (tid >= 64 && tid < 128) {          // wave 1: bucket base = capped prefix sum
    int l = tid - 64;
    int ssum = 0;
    for (int i = l; i < b; i += 64) {
      int c = bucket_cursor[i];
      ssum += (c < BCAP) ? c : BCAP;
    }
    #pragma unroll
    for (int d = 1; d < 64; d <<= 1) ssum += __shfl_xor(ssum, d);
    if (l == 0) base_s = ssum;
  }
  if (tid < KEYS) { nhist[tid] = 0; degf[tid] = 0.f; }
  __syncthreads();
  const uint2* sb = staged + (size_t)b * BCAP;
  for (int i = tid; i < cnt; i += 1024) {
    uint2 rec = sb[i];
    cache[i] = rec;
    int key = (((rec.x >> 19) & 127) << 3) | ((rec.x >> 16) & 7);
    atomicAdd(&nhist[key], 1);
    atomicAdd(&degf[key], __uint_as_float(rec.y));
  }
  __syncthreads();
  if (tid < 64) {    // wave 0: scan 1024 keys (16 chunks of 64, serial carry)
    int carry = 0;
    #pragma unroll
    for (int s = 0; s < KEYS / 64; s++) {
      int v = nhist[s * 64 + tid];
      int inc = v;
      #pragma unroll
      for (int d = 1; d < 64; d <<= 1) {
        int tt = __shfl_up(inc, d);
        if (tid >= d) inc += tt;
      }
      ncur[s * 64 + tid] = carry + inc - v;
      carry += __shfl(inc, 63);
    }
  }
  __syncthreads();
  int base = base_s;
  int gk0 = b * KEYS;
  int nk = NNODES * NREL - gk0; if (nk > KEYS) nk = KEYS;
  if (tid < nk) roff[gk0 + tid] = base + ncur[tid];
  if (b == 0 && tid == 0) roff[NNODES * NREL] = NEDGES;
  if (tid < KEYS) {
    float d = degf[tid];
    degf[tid] = (d != 0.f) ? (1.0f / d) : 0.f;
  }
  __syncthreads();
  for (int i = tid; i < cnt; i += 1024) {
    uint2 rec = cache[i];
    int key = (((rec.x >> 19) & 127) << 3) | ((rec.x >> 16) & 7);
    int pos = atomicAdd(&ncur[key], 1);
    float sc = __uint_as_float(rec.y) * degf[key];
    unsigned mx = ((rec.x & 0xFFFF) << 7) | ((rec.x >> 16) & 7);   // src*128 | rel
    meta[base + pos] = make_uint2(mx, __float_as_uint(sc));
  }
}

// K3: FUSED aggregate + output GEMM. Block = 16 nodes (4 waves x 4 nodes serial).
// Edge engine: FLAT per-node loop, unroll x8: 8 uniform s_loads of meta -> 8
// independent SGPR-base gathers in flight -> per edge 8 v_fmac with scalar
// cselect'd scale (SALU). No per-rel segment loops.
__global__ __launch_bounds__(256) void fused_kernel(const int* __restrict__ roff,
                                                    const uint2* __restrict__ meta,
                                                    const unsigned short* __restrict__ xb,
                                                    const unsigned short* __restrict__ Bf2,
                                                    const float* __restrict__ bsum,
                                                    float* __restrict__ out) {
  __shared__ unsigned short At[16 * APITCH];   // 18.25 KB
  int tid  = threadIdx.x;
  int wave = tid >> 6;
  int lane = tid & 63;
  int nodeBase = blockIdx.x * 16;
  const char* xbb = (const char*)xb;
  int lane2 = lane * 2;

  #pragma unroll
  for (int i = 0; i < 4; i++) {
    int row  = wave * 4 + i;
    int node = __builtin_amdgcn_readfirstlane(nodeBase + row);
    int e0 = roff[node * NREL];
    int e1 = roff[node * NREL + NREL];

    float acc[8];
    #pragma unroll
    for (int r = 0; r < 8; r++) acc[r] = 0.f;

    int e = e0;
    for (; e + 8 <= e1; e += 8) {          // main: 8 gathers in flight
      uint2 m0 = meta[e],     m1 = meta[e + 1], m2 = meta[e + 2], m3 = meta[e + 3];
      uint2 m4 = meta[e + 4], m5 = meta[e + 5], m6 = meta[e + 6], m7 = meta[e + 7];
      float v0 = bf2f(*(const unsigned short*)(xbb + (m0.x & ~127u) + lane2));
      float v1 = bf2f(*(const unsigned short*)(xbb + (m1.x & ~127u) + lane2));
      float v2 = bf2f(*(const unsigned short*)(xbb + (m2.x & ~127u) + lane2));
      float v3 = bf2f(*(const unsigned short*)(xbb + (m3.x & ~127u) + lane2));
      float v4 = bf2f(*(const unsigned short*)(xbb + (m4.x & ~127u) + lane2));
      float v5 = bf2f(*(const unsigned short*)(xbb + (m5.x & ~127u) + lane2));
      float v6 = bf2f(*(const unsigned short*)(xbb + (m6.x & ~127u) + lane2));
      float v7 = bf2f(*(const unsigned short*)(xbb + (m7.x & ~127u) + lane2));
      #define ACCUM(M, V) {                                                \
        int rel = (int)((M).x & 7u);                                       \
        float sc = __uint_as_float((M).y);                                 \
        _Pragma("unroll")                                                  \
        for (int r = 0; r < 8; r++) acc[r] += ((rel == r) ? sc : 0.f) * (V); }
      ACCUM(m0, v0) ACCUM(m1, v1) ACCUM(m2, v2) ACCUM(m3, v3)
      ACCUM(m4, v4) ACCUM(m5, v5) ACCUM(m6, v6) ACCUM(m7, v7)
    }
    for (; e < e1; e++) {                   // tail
      uint2 m0 = meta[e];
      float v0 = bf2f(*(const unsigned short*)(xbb + (m0.x & ~127u) + lane2));
      ACCUM(m0, v0)
    }
    #undef ACCUM

    unsigned short* ar = At + row * APITCH;
    #pragma unroll
    for (int r = 0; r < 8; r++) ar[r * 64 + lane] = f2bf(acc[r]);
    ar[512 + lane] = xb[(size_t)(nodeBase + row) * 64 + lane];   // self-loop block
  }
  __syncthreads();

  // Phase 2: MFMA; this wave's col tile = wave.
  int q = lane >> 4;
  int m = lane & 15;
  float4v acc4 = {0.f, 0.f, 0.f, 0.f};
  const short8* Bp = (const short8*)Bf2;
  #pragma unroll
  for (int ks = 0; ks < 18; ks++) {
    short8 a = *(const short8*)(At + m * APITCH + ks * 32 + q * 8);
    short8 bfr = Bp[(ks * 4 + wave) * 64 + lane];
    acc4 = __builtin_amdgcn_mfma_f32_16x16x32_bf16(a, bfr, acc4, 0, 0, 0);
  }
  int c = wave * 16 + m;
  float bias = bsum[c];
  #pragma unroll
  for (int rr = 0; rr < 4; rr++) {
    out[(size_t)(nodeBase + q * 4 + rr) * 64 + c] = fmaxf(acc4[rr] + bias, 0.0f);
  }
}

extern "C" void kernel_launch(void* const* d_in, const int* in_sizes, int n_in,
                              void* d_out, int out_size, void* d_ws, size_t ws_size,
                              hipStream_t stream) {
  const float* x     = (const float*)d_in[0];
  const int*   esrc  = (const int*)d_in[1];
  const int*   edst  = (const int*)d_in[2];
  const int*   erel  = (const int*)d_in[3];
  const float* ew    = (const float*)d_in[4];
  const float* Wlin  = (const float*)d_in[5];
  const float* blin  = (const float*)d_in[6];
  const float* Wself = (const float*)d_in[7];
  const float* bself = (const float*)d_in[8];
  float* out = (float*)d_out;

  char* ws = (char*)d_ws;
  size_t off = 0;
  auto alloc = [&](size_t bytes) -> void* {
    void* p = ws + off;
    off += (bytes + 255) & ~(size_t)255;
    return p;
  };
  int*            bucket_cursor = (int*)alloc((size_t)NBUCK * sizeof(int));           // zeroed in prep_cast
  int*            roff    = (int*)alloc((size_t)(NNODES * NREL + 8) * sizeof(int));   // 1.6 MB
  uint2*          staged  = (uint2*)alloc((size_t)NBUCK * BCAP * sizeof(uint2));      // 9.2 MB
  uint2*          meta    = (uint2*)alloc((size_t)NEDGES * sizeof(uint2));            // 8 MB
  unsigned short* Bf2     = (unsigned short*)alloc((size_t)18 * 4 * 64 * 8 * sizeof(unsigned short));
  float*          bsum    = (float*)alloc(64 * sizeof(float));
  unsigned short* xb      = (unsigned short*)alloc((size_t)NNODES * DIM * sizeof(unsigned short));  // 6.4 MB

  const int E4 = NEDGES / 4;
  prep_cast_kernel<<<CASTBLK + PREPBLK, 256, 0, stream>>>(Wlin, Wself, blin, bself,
                                                          (const float4*)x, Bf2, bsum,
                                                          (us4*)xb, bucket_cursor);
  binscatter_kernel<<<(E4 + 1023) / 1024, 1024, 0, stream>>>((const int4*)esrc, (const int4*)edst,
                                                             (const int4*)erel, (const float4*)ew,
                                                             bucket_cursor, staged, E4);
  csrbuild_kernel<<<NBUCK, 1024, 0, stream>>>(bucket_cursor, staged, meta, roff);
  fused_kernel<<<NBLK, 256, 0, stream>>>(roff, meta, xb, Bf2, bsum, out);
}

// Round 10
// 171.296 us; speedup vs baseline: 1.1005x; 1.1005x over previous
//
#include <hip/hip_runtime.h>
#include <stdint.h>

// Problem constants (from reference)
#define NNODES 50000
#define NEDGES 1000000
#define DIM    64
#define NREL   8
#define NBUCK  391          // ceil(50000/128); bucket = dst >> 7 (128-node range)
#define BCAP   2944         // per-bucket staging capacity (expected ~2558, +7.6 sigma)
#define KEYS   1024         // 128 nodes x 8 rels per bucket
#define NBLK   3125         // 50000 / 16 output blocks
#define APITCH 584          // LDS bf16 tile pitch (576 + 8)

typedef __attribute__((ext_vector_type(8))) short short8;
typedef __attribute__((ext_vector_type(4))) float float4v;
typedef __attribute__((ext_vector_type(4))) unsigned short us4;

__device__ __forceinline__ float bf2f(unsigned short u) {
  return __uint_as_float(((unsigned int)u) << 16);
}
__device__ __forceinline__ unsigned short f2bf(float f) {
  unsigned int u = __float_as_uint(f);
  unsigned int r = (u + 0x7FFF + ((u >> 16) & 1)) >> 16;   // round-nearest-even
  return (unsigned short)r;
}

#define CASTBLK ((NNODES * DIM / 4 + 255) / 256)
#define PREPBLK ((18 * 4 * 64 * 8 + 255) / 256)

// K0: fused prep (B fragments + bias) and x f32->bf16 cast; zero bucket_cursor.
__global__ void prep_cast_kernel(const float* __restrict__ Wlin,
                                 const float* __restrict__ Wself,
                                 const float* __restrict__ blin,
                                 const float* __restrict__ bself,
                                 const float4* __restrict__ x4,
                                 unsigned short* __restrict__ Bf2,
                                 float* __restrict__ bsum,
                                 us4* __restrict__ xb,
                                 int* __restrict__ bucket_cursor) {
  int gt = blockIdx.x * 256 + threadIdx.x;
  if (gt < NBUCK) bucket_cursor[gt] = 0;
  if (gt < 64) bsum[gt] = blin[gt] + bself[gt];
  if (blockIdx.x < CASTBLK) {
    int t = gt;
    if (t < NNODES * DIM / 4) {
      float4 v = x4[t];
      us4 o;
      o.x = f2bf(v.x); o.y = f2bf(v.y); o.z = f2bf(v.z); o.w = f2bf(v.w);
      xb[t] = o;
    }
  } else {
    int t = (blockIdx.x - CASTBLK) * 256 + threadIdx.x;
    if (t < 18 * 4 * 64 * 8) {
      int j  = t & 7;
      int l  = (t >> 3) & 63;
      int ct = (t >> 9) & 3;
      int ks = t >> 11;
      int k = ks * 32 + (l >> 4) * 8 + j;
      int c = ct * 16 + (l & 15);
      float v = (k < 512) ? Wlin[(size_t)k * 64 + c] : Wself[(size_t)(k - 512) * 64 + c];
      Bf2[t] = f2bf(v);
    }
  }
}

// K1: binned scatter with block-local LDS counting sort + coalesced run flush.
// Record: x = src(16) | rel(3)<<16 | dst_low7(7)<<19, y = w bits.
__global__ __launch_bounds__(1024) void binscatter_kernel(
    const int4* __restrict__ src4, const int4* __restrict__ dst4,
    const int4* __restrict__ rel4, const float4* __restrict__ w4,
    int* __restrict__ bucket_cursor, uint2* __restrict__ staged, int E4) {
  __shared__ int lhist[NBUCK];
  __shared__ int lscan[NBUCK];
  __shared__ int lbaseg[NBUCK];
  __shared__ uint2 lrec[4096];              // 32 KB
  __shared__ unsigned short lbuck[4096];    // 8 KB
  int tid = threadIdx.x;
  if (tid < NBUCK) lhist[tid] = 0;
  __syncthreads();
  int t = blockIdx.x * 1024 + tid;
  bool valid = t < E4;
  int4 s = {0,0,0,0}, d = {0,0,0,0}, r = {0,0,0,0};
  float4 w = {0.f,0.f,0.f,0.f};
  if (valid) { s = src4[t]; d = dst4[t]; r = rel4[t]; w = w4[t]; }
  int b0=0,b1=0,b2=0,b3=0,p0=0,p1=0,p2=0,p3=0;
  if (valid) {
    b0 = d.x >> 7; p0 = atomicAdd(&lhist[b0], 1);
    b1 = d.y >> 7; p1 = atomicAdd(&lhist[b1], 1);
    b2 = d.z >> 7; p2 = atomicAdd(&lhist[b2], 1);
    b3 = d.w >> 7; p3 = atomicAdd(&lhist[b3], 1);
  }
  __syncthreads();
  if (tid < 64) {                 // wave 0: exclusive scan of 391 counts
    int carry = 0;
    #pragma unroll
    for (int c = 0; c < 7; c++) {
      int i = c * 64 + tid;
      int v = (i < NBUCK) ? lhist[i] : 0;
      int inc = v;
      #pragma unroll
      for (int dd = 1; dd < 64; dd <<= 1) {
        int tt = __shfl_up(inc, dd);
        if (tid >= dd) inc += tt;
      }
      if (i < NBUCK) lscan[i] = carry + inc - v;
      carry += __shfl(inc, 63);
    }
  }
  __syncthreads();
  if (valid) {
    int q;
    q = lscan[b0] + p0; lrec[q] = make_uint2((unsigned)s.x | ((unsigned)r.x << 16) | ((unsigned)(d.x & 127) << 19), __float_as_uint(w.x)); lbuck[q] = (unsigned short)b0;
    q = lscan[b1] + p1; lrec[q] = make_uint2((unsigned)s.y | ((unsigned)r.y << 16) | ((unsigned)(d.y & 127) << 19), __float_as_uint(w.y)); lbuck[q] = (unsigned short)b1;
    q = lscan[b2] + p2; lrec[q] = make_uint2((unsigned)s.z | ((unsigned)r.z << 16) | ((unsigned)(d.z & 127) << 19), __float_as_uint(w.z)); lbuck[q] = (unsigned short)b2;
    q = lscan[b3] + p3; lrec[q] = make_uint2((unsigned)s.w | ((unsigned)r.w << 16) | ((unsigned)(d.w & 127) << 19), __float_as_uint(w.w)); lbuck[q] = (unsigned short)b3;
  }
  if (tid < NBUCK && lhist[tid] > 0)
    lbaseg[tid] = atomicAdd(&bucket_cursor[tid], lhist[tid]);
  __syncthreads();
  int cntblk = NEDGES - blockIdx.x * 4096;
  if (cntblk > 4096) cntblk = 4096;
  for (int i = tid; i < cntblk; i += 1024) {     // linear LDS read, run-coalesced store
    int b = lbuck[i];
    int idx = lbaseg[b] + (i - lscan[b]);
    if (idx < BCAP) staged[(size_t)b * BCAP + idx] = lrec[i];
  }
}

// K2: per-bucket: LDS-cache records, 1024-key hist+scan, write per-(node,rel)
// segment offsets roff[] and meta = (src*128 byte-offset, w/deg), grouped by (node,rel).
__global__ __launch_bounds__(1024) void csrbuild_kernel(
    const int* __restrict__ bucket_cursor,
    const uint2* __restrict__ staged, uint2* __restrict__ meta, int* __restrict__ roff) {
  __shared__ uint2 cache[BCAP];                 // 23.0 KB
  __shared__ int   nhist[KEYS];
  __shared__ int   ncur[KEYS];
  __shared__ float degf[KEYS];
  __shared__ int   base_s;
  int b = blockIdx.x;
  int tid = threadIdx.x;
  int cnt  = bucket_cursor[b];
  if (cnt > BCAP) cnt = BCAP;
  if (tid >= 64 && tid < 128) {          // wave 1: bucket base = capped prefix sum
    int l = tid - 64;
    int ssum = 0;
    for (int i = l; i < b; i += 64) {
      int c = bucket_cursor[i];
      ssum += (c < BCAP) ? c : BCAP;
    }
    #pragma unroll
    for (int d = 1; d < 64; d <<= 1) ssum += __shfl_xor(ssum, d);
    if (l == 0) base_s = ssum;
  }
  if (tid < KEYS) { nhist[tid] = 0; degf[tid] = 0.f; }
  __syncthreads();
  const uint2* sb = staged + (size_t)b * BCAP;
  for (int i = tid; i < cnt; i += 1024) {
    uint2 rec = sb[i];
    cache[i] = rec;
    int key = (((rec.x >> 19) & 127) << 3) | ((rec.x >> 16) & 7);
    atomicAdd(&nhist[key], 1);
    atomicAdd(&degf[key], __uint_as_float(rec.y));
  }
  __syncthreads();
  if (tid < 64) {    // wave 0: scan 1024 keys (16 chunks of 64, serial carry)
    int carry = 0;
    #pragma unroll
    for (int s = 0; s < KEYS / 64; s++) {
      int v = nhist[s * 64 + tid];
      int inc = v;
      #pragma unroll
      for (int d = 1; d < 64; d <<= 1) {
        int tt = __shfl_up(inc, d);
        if (tid >= d) inc += tt;
      }
      ncur[s * 64 + tid] = carry + inc - v;
      carry += __shfl(inc, 63);
    }
  }
  __syncthreads();
  int base = base_s;
  int gk0 = b * KEYS;
  int nk = NNODES * NREL - gk0; if (nk > KEYS) nk = KEYS;
  if (tid < nk) roff[gk0 + tid] = base + ncur[tid];
  if (b == 0 && tid == 0) roff[NNODES * NREL] = NEDGES;
  if (tid < KEYS) {
    float d = degf[tid];
    degf[tid] = (d != 0.f) ? (1.0f / d) : 0.f;
  }
  __syncthreads();
  for (int i = tid; i < cnt; i += 1024) {
    uint2 rec = cache[i];
    int key = (((rec.x >> 19) & 127) << 3) | ((rec.x >> 16) & 7);
    int pos = atomicAdd(&ncur[key], 1);
    float sc = __uint_as_float(rec.y) * degf[key];
    meta[base + pos] = make_uint2((rec.x & 0xFFFF) << 7, __float_as_uint(sc));  // src*128 bytes
  }
}

// K3: FUSED aggregate + output GEMM. Block = 16 nodes (4 waves x 4 nodes serial).
// Edge engine: rel-interleaved clamped loop. Per j-iteration: 8 independent
// scalar-addressed gathers (one per rel, index clamped to its segment) then
// 8 v_fmac with scalar-selected scale (0 beyond segment end). 1 fmac/edge,
// MLP ~8, clamped duplicates re-hit L1.
__global__ __launch_bounds__(256) void fused_kernel(const int* __restrict__ roff,
                                                    const uint2* __restrict__ meta,
                                                    const unsigned short* __restrict__ xb,
                                                    const unsigned short* __restrict__ Bf2,
                                                    const float* __restrict__ bsum,
                                                    float* __restrict__ out) {
  __shared__ unsigned short At[16 * APITCH];   // 18.25 KB
  int tid  = threadIdx.x;
  int wave = tid >> 6;
  int lane = tid & 63;
  int nodeBase = blockIdx.x * 16;
  const char* xbb = (const char*)xb;
  int lane2 = lane * 2;

  #pragma unroll
  for (int i = 0; i < 4; i++) {
    int row  = wave * 4 + i;
    int node = __builtin_amdgcn_readfirstlane(nodeBase + row);
    int bnd = 0;
    if (lane < 9) bnd = roff[node * NREL + lane];

    int eb[9];
    #pragma unroll
    for (int k = 0; k < 9; k++) eb[k] = __builtin_amdgcn_readlane(bnd, k);  // SGPR bounds

    int len[8], cap[8];
    int maxlen = 0;
    #pragma unroll
    for (int r = 0; r < 8; r++) {
      len[r] = eb[r + 1] - eb[r];
      int lm1 = (len[r] > 0) ? (len[r] - 1) : 0;
      int c = eb[r] + lm1;
      cap[r] = (c < NEDGES - 1) ? c : (NEDGES - 1);
      maxlen = (len[r] > maxlen) ? len[r] : maxlen;
    }

    float acc[8];
    #pragma unroll
    for (int r = 0; r < 8; r++) acc[r] = 0.f;

    for (int j = 0; j < maxlen; j++) {
      uint2 mm[8];
      #pragma unroll
      for (int r = 0; r < 8; r++) {
        int idx = eb[r] + j;
        idx = (idx < cap[r]) ? idx : cap[r];
        mm[r] = meta[idx];                               // uniform -> s_load
      }
      float vv[8];
      #pragma unroll
      for (int r = 0; r < 8; r++) {
        vv[r] = bf2f(*(const unsigned short*)(xbb + mm[r].x + lane2));  // 8 gathers in flight
      }
      #pragma unroll
      for (int r = 0; r < 8; r++) {
        float sc = (j < len[r]) ? __uint_as_float(mm[r].y) : 0.f;       // scalar cselect
        acc[r] += sc * vv[r];
      }
    }

    unsigned short* ar = At + row * APITCH;
    #pragma unroll
    for (int r = 0; r < 8; r++) ar[r * 64 + lane] = f2bf(acc[r]);
    ar[512 + lane] = xb[(size_t)(nodeBase + row) * 64 + lane];   // self-loop block
  }
  __syncthreads();

  // Phase 2: MFMA; this wave's col tile = wave.
  int q = lane >> 4;
  int m = lane & 15;
  float4v acc4 = {0.f, 0.f, 0.f, 0.f};
  const short8* Bp = (const short8*)Bf2;
  #pragma unroll
  for (int ks = 0; ks < 18; ks++) {
    short8 a = *(const short8*)(At + m * APITCH + ks * 32 + q * 8);
    short8 bfr = Bp[(ks * 4 + wave) * 64 + lane];
    acc4 = __builtin_amdgcn_mfma_f32_16x16x32_bf16(a, bfr, acc4, 0, 0, 0);
  }
  int c = wave * 16 + m;
  float bias = bsum[c];
  #pragma unroll
  for (int rr = 0; rr < 4; rr++) {
    out[(size_t)(nodeBase + q * 4 + rr) * 64 + c] = fmaxf(acc4[rr] + bias, 0.0f);
  }
}

extern "C" void kernel_launch(void* const* d_in, const int* in_sizes, int n_in,
                              void* d_out, int out_size, void* d_ws, size_t ws_size,
                              hipStream_t stream) {
  const float* x     = (const float*)d_in[0];
  const int*   esrc  = (const int*)d_in[1];
  const int*   edst  = (const int*)d_in[2];
  const int*   erel  = (const int*)d_in[3];
  const float* ew    = (const float*)d_in[4];
  const float* Wlin  = (const float*)d_in[5];
  const float* blin  = (const float*)d_in[6];
  const float* Wself = (const float*)d_in[7];
  const float* bself = (const float*)d_in[8];
  float* out = (float*)d_out;

  char* ws = (char*)d_ws;
  size_t off = 0;
  auto alloc = [&](size_t bytes) -> void* {
    void* p = ws + off;
    off += (bytes + 255) & ~(size_t)255;
    return p;
  };
  int*            bucket_cursor = (int*)alloc((size_t)NBUCK * sizeof(int));           // zeroed in prep_cast
  int*            roff    = (int*)alloc((size_t)(NNODES * NREL + 8) * sizeof(int));   // 1.6 MB
  uint2*          staged  = (uint2*)alloc((size_t)NBUCK * BCAP * sizeof(uint2));      // 9.2 MB
  uint2*          meta    = (uint2*)alloc((size_t)(NEDGES + 8) * sizeof(uint2));      // 8 MB
  unsigned short* Bf2     = (unsigned short*)alloc((size_t)18 * 4 * 64 * 8 * sizeof(unsigned short));
  float*          bsum    = (float*)alloc(64 * sizeof(float));
  unsigned short* xb      = (unsigned short*)alloc((size_t)NNODES * DIM * sizeof(unsigned short));  // 6.4 MB

  const int E4 = NEDGES / 4;
  prep_cast_kernel<<<CASTBLK + PREPBLK, 256, 0, stream>>>(Wlin, Wself, blin, bself,
                                                          (const float4*)x, Bf2, bsum,
                                                          (us4*)xb, bucket_cursor);
  binscatter_kernel<<<(E4 + 1023) / 1024, 1024, 0, stream>>>((const int4*)esrc, (const int4*)edst,
                                                             (const int4*)erel, (const float4*)ew,
                                                             bucket_cursor, staged, E4);
  csrbuild_kernel<<<NBUCK, 1024, 0, stream>>>(bucket_cursor, staged, meta, roff);
  fused_kernel<<<NBLK, 256, 0, stream>>>(roff, meta, xb, Bf2, bsum, out);
}

// Round 11
// 166.519 us; speedup vs baseline: 1.1321x; 1.0287x over previous
//
#include <hip/hip_runtime.h>
#include <stdint.h>

// Problem constants (from reference)
#define NNODES 50000
#define NEDGES 1000000
#define DIM    64
#define NREL   8
#define NBUCK  391          // ceil(50000/128); bucket = dst >> 7 (128-node range)
#define BCAP   2944         // per-bucket staging capacity (expected ~2558, +7.6 sigma)
#define KEYS   1024         // 128 nodes x 8 rels per bucket
#define NBLK   3125         // 50000 / 16 output blocks
#define APITCH 584          // LDS bf16 tile pitch (576 + 8)

typedef __attribute__((ext_vector_type(8))) short short8;
typedef __attribute__((ext_vector_type(4))) float float4v;
typedef __attribute__((ext_vector_type(4))) unsigned short us4;

__device__ __forceinline__ float bf2f(unsigned short u) {
  return __uint_as_float(((unsigned int)u) << 16);
}
__device__ __forceinline__ unsigned short f2bf(float f) {
  unsigned int u = __float_as_uint(f);
  unsigned int r = (u + 0x7FFF + ((u >> 16) & 1)) >> 16;   // round-nearest-even
  return (unsigned short)r;
}

#define CASTBLK ((NNODES * DIM / 4 + 255) / 256)
#define PREPBLK ((18 * 4 * 64 * 8 + 255) / 256)

// K0: fused prep (B fragments + bias) and x f32->bf16 cast; zero bucket_cursor.
__global__ void prep_cast_kernel(const float* __restrict__ Wlin,
                                 const float* __restrict__ Wself,
                                 const float* __restrict__ blin,
                                 const float* __restrict__ bself,
                                 const float4* __restrict__ x4,
                                 unsigned short* __restrict__ Bf2,
                                 float* __restrict__ bsum,
                                 us4* __restrict__ xb,
                                 int* __restrict__ bucket_cursor) {
  int gt = blockIdx.x * 256 + threadIdx.x;
  if (gt < NBUCK) bucket_cursor[gt] = 0;
  if (gt < 64) bsum[gt] = blin[gt] + bself[gt];
  if (blockIdx.x < CASTBLK) {
    int t = gt;
    if (t < NNODES * DIM / 4) {
      float4 v = x4[t];
      us4 o;
      o.x = f2bf(v.x); o.y = f2bf(v.y); o.z = f2bf(v.z); o.w = f2bf(v.w);
      xb[t] = o;
    }
  } else {
    int t = (blockIdx.x - CASTBLK) * 256 + threadIdx.x;
    if (t < 18 * 4 * 64 * 8) {
      int j  = t & 7;
      int l  = (t >> 3) & 63;
      int ct = (t >> 9) & 3;
      int ks = t >> 11;
      int k = ks * 32 + (l >> 4) * 8 + j;
      int c = ct * 16 + (l & 15);
      float v = (k < 512) ? Wlin[(size_t)k * 64 + c] : Wself[(size_t)(k - 512) * 64 + c];
      Bf2[t] = f2bf(v);
    }
  }
}

// K1: binned scatter with block-local LDS counting sort + coalesced run flush.
// Record: x = src(16) | rel(3)<<16 | dst_low7(7)<<19, y = w bits.
__global__ __launch_bounds__(1024) void binscatter_kernel(
    const int4* __restrict__ src4, const int4* __restrict__ dst4,
    const int4* __restrict__ rel4, const float4* __restrict__ w4,
    int* __restrict__ bucket_cursor, uint2* __restrict__ staged, int E4) {
  __shared__ int lhist[NBUCK];
  __shared__ int lscan[NBUCK];
  __shared__ int lbaseg[NBUCK];
  __shared__ uint2 lrec[4096];              // 32 KB
  __shared__ unsigned short lbuck[4096];    // 8 KB
  int tid = threadIdx.x;
  if (tid < NBUCK) lhist[tid] = 0;
  __syncthreads();
  int t = blockIdx.x * 1024 + tid;
  bool valid = t < E4;
  int4 s = {0,0,0,0}, d = {0,0,0,0}, r = {0,0,0,0};
  float4 w = {0.f,0.f,0.f,0.f};
  if (valid) { s = src4[t]; d = dst4[t]; r = rel4[t]; w = w4[t]; }
  int b0=0,b1=0,b2=0,b3=0,p0=0,p1=0,p2=0,p3=0;
  if (valid) {
    b0 = d.x >> 7; p0 = atomicAdd(&lhist[b0], 1);
    b1 = d.y >> 7; p1 = atomicAdd(&lhist[b1], 1);
    b2 = d.z >> 7; p2 = atomicAdd(&lhist[b2], 1);
    b3 = d.w >> 7; p3 = atomicAdd(&lhist[b3], 1);
  }
  __syncthreads();
  if (tid < 64) {                 // wave 0: exclusive scan of 391 counts
    int carry = 0;
    #pragma unroll
    for (int c = 0; c < 7; c++) {
      int i = c * 64 + tid;
      int v = (i < NBUCK) ? lhist[i] : 0;
      int inc = v;
      #pragma unroll
      for (int dd = 1; dd < 64; dd <<= 1) {
        int tt = __shfl_up(inc, dd);
        if (tid >= dd) inc += tt;
      }
      if (i < NBUCK) lscan[i] = carry + inc - v;
      carry += __shfl(inc, 63);
    }
  }
  __syncthreads();
  if (valid) {
    int q;
    q = lscan[b0] + p0; lrec[q] = make_uint2((unsigned)s.x | ((unsigned)r.x << 16) | ((unsigned)(d.x & 127) << 19), __float_as_uint(w.x)); lbuck[q] = (unsigned short)b0;
    q = lscan[b1] + p1; lrec[q] = make_uint2((unsigned)s.y | ((unsigned)r.y << 16) | ((unsigned)(d.y & 127) << 19), __float_as_uint(w.y)); lbuck[q] = (unsigned short)b1;
    q = lscan[b2] + p2; lrec[q] = make_uint2((unsigned)s.z | ((unsigned)r.z << 16) | ((unsigned)(d.z & 127) << 19), __float_as_uint(w.z)); lbuck[q] = (unsigned short)b2;
    q = lscan[b3] + p3; lrec[q] = make_uint2((unsigned)s.w | ((unsigned)r.w << 16) | ((unsigned)(d.w & 127) << 19), __float_as_uint(w.w)); lbuck[q] = (unsigned short)b3;
  }
  if (tid < NBUCK && lhist[tid] > 0)
    lbaseg[tid] = atomicAdd(&bucket_cursor[tid], lhist[tid]);
  __syncthreads();
  int cntblk = NEDGES - blockIdx.x * 4096;
  if (cntblk > 4096) cntblk = 4096;
  for (int i = tid; i < cntblk; i += 1024) {     // linear LDS read, run-coalesced store
    int b = lbuck[i];
    int idx = lbaseg[b] + (i - lscan[b]);
    if (idx < BCAP) staged[(size_t)b * BCAP + idx] = lrec[i];
  }
}

// K2: per-bucket CSR build. Pass A ranks records into inv[] (inverse permutation);
// pass B writes meta[] COALESCED (thread = output slot). roff = per-(node,rel)
// segment offsets; meta = (src*128 byte-offset, w/deg), grouped by (node,rel).
__global__ __launch_bounds__(1024) void csrbuild_kernel(
    const int* __restrict__ bucket_cursor,
    const uint2* __restrict__ staged, uint2* __restrict__ meta, int* __restrict__ roff) {
  __shared__ uint2 cache[BCAP];                 // 23.0 KB
  __shared__ short inv[BCAP];                   // 5.75 KB
  __shared__ int   nhist[KEYS];
  __shared__ int   ncur[KEYS];
  __shared__ float degf[KEYS];
  __shared__ int   base_s;
  int b = blockIdx.x;
  int tid = threadIdx.x;
  int cnt  = bucket_cursor[b];
  if (cnt > BCAP) cnt = BCAP;
  if (tid >= 64 && tid < 128) {          // wave 1: bucket base = capped prefix sum
    int l = tid - 64;
    int ssum = 0;
    for (int i = l; i < b; i += 64) {
      int c = bucket_cursor[i];
      ssum += (c < BCAP) ? c : BCAP;
    }
    #pragma unroll
    for (int d = 1; d < 64; d <<= 1) ssum += __shfl_xor(ssum, d);
    if (l == 0) base_s = ssum;
  }
  if (tid < KEYS) { nhist[tid] = 0; degf[tid] = 0.f; }
  __syncthreads();
  const uint2* sb = staged + (size_t)b * BCAP;
  for (int i = tid; i < cnt; i += 1024) {
    uint2 rec = sb[i];
    cache[i] = rec;
    int key = (((rec.x >> 19) & 127) << 3) | ((rec.x >> 16) & 7);
    atomicAdd(&nhist[key], 1);
    atomicAdd(&degf[key], __uint_as_float(rec.y));
  }
  __syncthreads();
  if (tid < 64) {    // wave 0: scan 1024 keys (16 chunks of 64, serial carry)
    int carry = 0;
    #pragma unroll
    for (int s = 0; s < KEYS / 64; s++) {
      int v = nhist[s * 64 + tid];
      int inc = v;
      #pragma unroll
      for (int d = 1; d < 64; d <<= 1) {
        int tt = __shfl_up(inc, d);
        if (tid >= d) inc += tt;
      }
      ncur[s * 64 + tid] = carry + inc - v;
      carry += __shfl(inc, 63);
    }
  }
  __syncthreads();
  int base = base_s;
  int gk0 = b * KEYS;
  int nk = NNODES * NREL - gk0; if (nk > KEYS) nk = KEYS;
  if (tid < nk) roff[gk0 + tid] = base + ncur[tid];
  if (b == 0 && tid == 0) roff[NNODES * NREL] = NEDGES;
  if (tid < KEYS) {
    float d = degf[tid];
    degf[tid] = (d != 0.f) ? (1.0f / d) : 0.f;
  }
  __syncthreads();
  for (int i = tid; i < cnt; i += 1024) {        // pass A: rank -> inverse perm
    uint2 rec = cache[i];
    int key = (((rec.x >> 19) & 127) << 3) | ((rec.x >> 16) & 7);
    int pos = atomicAdd(&ncur[key], 1);
    inv[pos] = (short)i;
  }
  __syncthreads();
  for (int o = tid; o < cnt; o += 1024) {        // pass B: coalesced meta store
    int i = (int)inv[o];
    uint2 rec = cache[i];
    int key = (((rec.x >> 19) & 127) << 3) | ((rec.x >> 16) & 7);
    float sc = __uint_as_float(rec.y) * degf[key];
    meta[base + o] = make_uint2((rec.x & 0xFFFF) << 7, __float_as_uint(sc));  // src*128 bytes
  }
}

// K3: FUSED aggregate + output GEMM. Block = 16 nodes, 512 threads = 8 waves.
// Phase 1: each wave aggregates 2 nodes with the segmented scalar engine
// (uniform s_load meta -> SGPR-base gather -> 1 fmac/edge). Short chains +
// 32 waves/CU hide gather latency.
// Phase 2: waves 0-3 do one 16-col MFMA tile each of (16x576)@(576x64), +bias, relu.
__global__ __launch_bounds__(512) void fused_kernel(const int* __restrict__ roff,
                                                    const uint2* __restrict__ meta,
                                                    const unsigned short* __restrict__ xb,
                                                    const unsigned short* __restrict__ Bf2,
                                                    const float* __restrict__ bsum,
                                                    float* __restrict__ out) {
  __shared__ unsigned short At[16 * APITCH];   // 18.25 KB
  int tid  = threadIdx.x;
  int wave = tid >> 6;
  int lane = tid & 63;
  int nodeBase = blockIdx.x * 16;
  const char* xbb = (const char*)xb;
  int lane2 = lane * 2;

  #pragma unroll
  for (int i = 0; i < 2; i++) {
    int row  = wave * 2 + i;
    int node = __builtin_amdgcn_readfirstlane(nodeBase + row);
    int bnd = 0;
    if (lane < 9) bnd = roff[node * NREL + lane];

    int eb[9];
    #pragma unroll
    for (int k = 0; k < 9; k++) eb[k] = __builtin_amdgcn_readlane(bnd, k);  // SGPR bounds

    float acc[8];
    #pragma unroll
    for (int r = 0; r < 8; r++) acc[r] = 0.f;

    #pragma unroll
    for (int r = 0; r < 8; r++) {
      int e  = eb[r];
      int e1 = eb[r + 1];
      for (; e + 2 <= e1; e += 2) {
        uint2 m0 = meta[e];          // uniform -> s_load_dwordx2
        uint2 m1 = meta[e + 1];
        float v0 = bf2f(*(const unsigned short*)(xbb + m0.x + lane2));
        float v1 = bf2f(*(const unsigned short*)(xbb + m1.x + lane2));
        acc[r] += __uint_as_float(m0.y) * v0;
        acc[r] += __uint_as_float(m1.y) * v1;
      }
      if (e < e1) {
        uint2 m0 = meta[e];
        acc[r] += __uint_as_float(m0.y) * bf2f(*(const unsigned short*)(xbb + m0.x + lane2));
      }
    }
    unsigned short* ar = At + row * APITCH;
    #pragma unroll
    for (int r = 0; r < 8; r++) ar[r * 64 + lane] = f2bf(acc[r]);
    ar[512 + lane] = xb[(size_t)node * 64 + lane];   // self-loop block
  }
  __syncthreads();

  // Phase 2: MFMA on waves 0-3; wave = col tile.
  if (wave < 4) {
    int q = lane >> 4;
    int m = lane & 15;
    float4v acc4 = {0.f, 0.f, 0.f, 0.f};
    const short8* Bp = (const short8*)Bf2;
    #pragma unroll
    for (int ks = 0; ks < 18; ks++) {
      short8 a = *(const short8*)(At + m * APITCH + ks * 32 + q * 8);
      short8 bfr = Bp[(ks * 4 + wave) * 64 + lane];
      acc4 = __builtin_amdgcn_mfma_f32_16x16x32_bf16(a, bfr, acc4, 0, 0, 0);
    }
    int c = wave * 16 + m;
    float bias = bsum[c];
    #pragma unroll
    for (int rr = 0; rr < 4; rr++) {
      out[(size_t)(nodeBase + q * 4 + rr) * 64 + c] = fmaxf(acc4[rr] + bias, 0.0f);
    }
  }
}

extern "C" void kernel_launch(void* const* d_in, const int* in_sizes, int n_in,
                              void* d_out, int out_size, void* d_ws, size_t ws_size,
                              hipStream_t stream) {
  const float* x     = (const float*)d_in[0];
  const int*   esrc  = (const int*)d_in[1];
  const int*   edst  = (const int*)d_in[2];
  const int*   erel  = (const int*)d_in[3];
  const float* ew    = (const float*)d_in[4];
  const float* Wlin  = (const float*)d_in[5];
  const float* blin  = (const float*)d_in[6];
  const float* Wself = (const float*)d_in[7];
  const float* bself = (const float*)d_in[8];
  float* out = (float*)d_out;

  char* ws = (char*)d_ws;
  size_t off = 0;
  auto alloc = [&](size_t bytes) -> void* {
    void* p = ws + off;
    off += (bytes + 255) & ~(size_t)255;
    return p;
  };
  int*            bucket_cursor = (int*)alloc((size_t)NBUCK * sizeof(int));           // zeroed in prep_cast
  int*            roff    = (int*)alloc((size_t)(NNODES * NREL + 8) * sizeof(int));   // 1.6 MB
  uint2*          staged  = (uint2*)alloc((size_t)NBUCK * BCAP * sizeof(uint2));      // 9.2 MB
  uint2*          meta    = (uint2*)alloc((size_t)(NEDGES + 8) * sizeof(uint2));      // 8 MB
  unsigned short* Bf2     = (unsigned short*)alloc((size_t)18 * 4 * 64 * 8 * sizeof(unsigned short));
  float*          bsum    = (float*)alloc(64 * sizeof(float));
  unsigned short* xb      = (unsigned short*)alloc((size_t)NNODES * DIM * sizeof(unsigned short));  // 6.4 MB

  const int E4 = NEDGES / 4;
  prep_cast_kernel<<<CASTBLK + PREPBLK, 256, 0, stream>>>(Wlin, Wself, blin, bself,
                                                          (const float4*)x, Bf2, bsum,
                                                          (us4*)xb, bucket_cursor);
  binscatter_kernel<<<(E4 + 1023) / 1024, 1024, 0, stream>>>((const int4*)esrc, (const int4*)edst,
                                                             (const int4*)erel, (const float4*)ew,
                                                             bucket_cursor, staged, E4);
  csrbuild_kernel<<<NBUCK, 1024, 0, stream>>>(bucket_cursor, staged, meta, roff);
  fused_kernel<<<NBLK, 512, 0, stream>>>(roff, meta, xb, Bf2, bsum, out);
}